// Round 12
// baseline (62.941 us; speedup 1.0000x reference)
//
#include <hip/hip_runtime.h>

// LSTMStacked: B=3, T=262144, H=2, L=4.
// R12 = R11 scan (telescoped staircase, CHUNK=32, 1 wave/SIMD, pk-fma gates,
// merged 7-trans cell) + loss reduction FUSED into the scan kernel via the
// R3-proven done-counter pattern (saves the loss_final dispatch, ~5 us).
// Cost model (calibrated R5/R10/R11): trans ~16cy/inst wave64, cell = 190cy,
// kernel floor = 272 cells x 190cy ~= 21.5us -> trans-pipe issue-bound.
// Schedule (validated): t0base=a-45; joins at iters 8/16/24; L3 warms 24;
// store iters 48..79. Masked workers (t_l<0) = first block of each batch.

#define T_LEN   262144
#define TMAX    (T_LEN - 1)
#define BATCH   3
#define NCHUNK  8192
#define CHUNK   32
#define NELEM   (BATCH * T_LEN * 2)             // 1572864
#define NTHREADS 64
#define NBLOCKS (BATCH * NCHUNK * 2 / NTHREADS) // 768
#define BLK_PER_BATCH (NBLOCKS / BATCH)         // 256

typedef float v2f __attribute__((ext_vector_type(2)));

static constexpr float L2E = 1.4426950408889634f;
static constexpr float sSc = -L2E;        // sigmoid rows: sig = rcp(1+exp2(-L2E*x))
static constexpr float sTc = 2.0f * L2E;  // tanh rows / scaled-c domain

__device__ __forceinline__ float fexp2(float x) { return __builtin_amdgcn_exp2f(x); }
__device__ __forceinline__ float frcp (float x) { return __builtin_amdgcn_rcpf(x); }

// lane 2i <-> 2i+1 exchange, pure VALU (DPP quad_perm [1,0,3,2]).
__device__ __forceinline__ float pair_swap(float x) {
  return __int_as_float(__builtin_amdgcn_mov_dpp(__float_as_int(x), 0xB1, 0xF, 0xF, true));
}
__device__ __forceinline__ v2f pkfma(v2f a, v2f b, v2f c) {
  return __builtin_elementwise_fma(a, b, c);     // -> v_pk_fma_f32
}
__device__ __forceinline__ v2f splat(float s) { return (v2f){s, s}; }

struct Coef {  // packed pairs: IF = (gate_i, gate_f), GO = (gate_g, gate_o)
  v2f aIFS[4], aIFX[4], rIFS[4], rIFX[4], bIF[4];
  v2f aGOS[4], aGOX[4], rGOS[4], rGOX[4], bGO[4];
};

// One time step over the NL active layers. All cells read PRE-iteration
// state (cn/hn staged, write-back after) => skew semantics, independent cells.
template<int NL, bool MASK, bool STORE>
__device__ __forceinline__ void step(const Coef& cf, int j, int t0v,
    float2& preu, const float* __restrict__ inb, float* __restrict__ outb,
    float lvu, float& lsum,
    float (&Cc)[4], float (&hS)[4], float (&hX)[4])
{
  const float2 xv = preu;
  int tn = t0v + 8;
  if (MASK)  tn = tn < 0 ? 0 : tn;        // only first-block-of-batch path
  if (STORE) tn = tn > TMAX ? TMAX : tn;  // only last-chunk guard
  preu = *reinterpret_cast<const float2*>(inb + tn * 2);

  float cn[4], hn[4];
#pragma unroll
  for (int l = 0; l < NL; ++l) {
    const float iS = (l == 0) ? xv.x : hS[l-1];
    const float iX = (l == 0) ? xv.y : hX[l-1];
    v2f sIF = pkfma(cf.rIFX[l], splat(hX[l]), pkfma(cf.rIFS[l], splat(hS[l]),
              pkfma(cf.aIFX[l], splat(iX), pkfma(cf.aIFS[l], splat(iS), cf.bIF[l]))));
    v2f sGO = pkfma(cf.rGOX[l], splat(hX[l]), pkfma(cf.rGOS[l], splat(hS[l]),
              pkfma(cf.aGOX[l], splat(iX), pkfma(cf.aGOS[l], splat(iS), cf.bGO[l]))));
    const float Ei = fexp2(sIF.x), Ef = fexp2(sIF.y);
    const float Eg = fexp2(sGO.x), Eo = fexp2(sGO.y);
    // Merged cell (validated R7): cn = [Cc*P + sT*(Eg-1)*F1] / (P*F1),
    // P=(1+Ei)(1+Eg), F1=1+Ef;  hn = (Ec-1)/((1+Eo)(1+Ec)), Ec=exp2(cn).
    const float F1 = 1.f + Ef;
    const float P  = (1.f + Ei) * (1.f + Eg);
    const float Nn = fmaf(Cc[l], P, sTc * (Eg - 1.f) * F1);
    cn[l] = Nn * frcp(P * F1);
    const float Ec = fexp2(cn[l]);
    const float Q  = frcp((1.f + Eo) * (1.f + Ec));
    hn[l] = (Ec - 1.f) * Q;
  }
#pragma unroll
  for (int l = 0; l < NL; ++l) {
    if (MASK) {
      const bool act = t0v >= l;          // t_l = t0v - l >= 0
      Cc[l] = act ? cn[l] : 0.f;
      const float hm = act ? hn[l] : 0.f;
      hS[l] = hm; hX[l] = pair_swap(hm);
    } else {
      Cc[l] = cn[l]; hS[l] = hn[l]; hX[l] = pair_swap(hn[l]);
    }
  }
  if (STORE) {
    const float d = hS[3] - lvu;
    lsum = fmaf(d, d, lsum);
    if (j == 0) *reinterpret_cast<float2*>(outb + (t0v - 3) * 2)
                  = make_float2(hS[3], hX[3]);
  }
}

template<bool MASK>
__device__ __forceinline__ void scan(const Coef& cf, int j, int a,
    const float* __restrict__ inb, float* __restrict__ outb,
    const float* __restrict__ lab, float2 (&pre)[8], float& lsum,
    float (&Cc)[4], float (&hS)[4], float (&hX)[4])
{
  const int t0base = a - 45;
  // staircase warm: 8 iters L0; 8 iters L0-1; 8 iters L0-2; 24 iters all-4
#pragma unroll
  for (int u = 0; u < 8; ++u)
    step<1, MASK, false>(cf, j, t0base + u, pre[u], inb, outb, 0.f, lsum, Cc, hS, hX);
#pragma unroll
  for (int u = 0; u < 8; ++u)
    step<2, MASK, false>(cf, j, t0base + 8 + u, pre[u], inb, outb, 0.f, lsum, Cc, hS, hX);
#pragma unroll
  for (int u = 0; u < 8; ++u)
    step<3, MASK, false>(cf, j, t0base + 16 + u, pre[u], inb, outb, 0.f, lsum, Cc, hS, hX);
#pragma clang loop unroll(disable)
  for (int i = 24; i < 48; i += 8) {
#pragma unroll
    for (int u = 0; u < 8; ++u)
      step<4, MASK, false>(cf, j, t0base + i + u, pre[u], inb, outb, 0.f, lsum, Cc, hS, hX);
  }
  // store: 4 rolled passes of 8; labels double-buffered ONE PASS AHEAD so the
  // L2 label-load latency (~200-900 cy) never lands on the recurrence chain.
  float lvu[8];
#pragma unroll
  for (int u = 0; u < 8; ++u) lvu[u] = lab[(a + u) * 2 + j];
#pragma clang loop unroll(disable)
  for (int ip = 0; ip < 4; ++ip) {
    const int ipn = ip < 3 ? ip + 1 : 3;     // last pass re-reads its own (dead)
    float lvn[8];
#pragma unroll
    for (int u = 0; u < 8; ++u) lvn[u] = lab[(a + ipn * 8 + u) * 2 + j];
#pragma unroll
    for (int u = 0; u < 8; ++u)
      step<4, false, true>(cf, j, t0base + 48 + ip * 8 + u, pre[u], inb, outb,
                           lvu[u], lsum, Cc, hS, hX);
#pragma unroll
    for (int u = 0; u < 8; ++u) lvu[u] = lvn[u];
  }
}

__global__ __launch_bounds__(NTHREADS) void lstm_fused(
    const float* __restrict__ x,      // [B,T,2]
    float*       __restrict__ out,    // [B,T,2]
    const float* __restrict__ WihA,   // [4,8,2]
    const float* __restrict__ WhhA,   // [4,8,2]
    const float* __restrict__ bihA,   // [4,8]
    const float* __restrict__ bhhA,   // [4,8]
    const float* __restrict__ labels, // [B,T,2]
    float* __restrict__ part,         // [NBLOCKS]
    int*   __restrict__ done,         // [1], zeroed per call
    float* __restrict__ loss)         // out + NELEM
{
  const int gt = blockIdx.x * NTHREADS + threadIdx.x;
  const int w  = gt >> 1;            // worker = (batch, chunk)
  const int j  = gt & 1;             // hidden unit owned by this lane
  const int b  = w >> 13;            // w / NCHUNK (8192 workers per batch)
  const int k  = w & (NCHUNK - 1);
  const int jo = j ^ 1;

  Coef cf;
#pragma unroll
  for (int l = 0; l < 4; ++l) {
    const float* Wih = WihA + l * 16;
    const float* Whh = WhhA + l * 16;
    const float* bih = bihA + l * 8;
    const float* bhh = bhhA + l * 8;
    const int ri = j, rf = 2 + j, rg = 4 + j, ro = 6 + j;
    if (l == 0) {    // absolute x columns (iS = x.x, iX = x.y)
      cf.aIFS[0] = (v2f){sSc * Wih[ri*2+0], sSc * Wih[rf*2+0]};
      cf.aIFX[0] = (v2f){sSc * Wih[ri*2+1], sSc * Wih[rf*2+1]};
      cf.aGOS[0] = (v2f){sTc * Wih[rg*2+0], sSc * Wih[ro*2+0]};
      cf.aGOX[0] = (v2f){sTc * Wih[rg*2+1], sSc * Wih[ro*2+1]};
    } else {         // own/cross form (input = lower layer's hS/hX)
      cf.aIFS[l] = (v2f){sSc * Wih[ri*2+j],  sSc * Wih[rf*2+j]};
      cf.aIFX[l] = (v2f){sSc * Wih[ri*2+jo], sSc * Wih[rf*2+jo]};
      cf.aGOS[l] = (v2f){sTc * Wih[rg*2+j],  sSc * Wih[ro*2+j]};
      cf.aGOX[l] = (v2f){sTc * Wih[rg*2+jo], sSc * Wih[ro*2+jo]};
    }
    cf.rIFS[l] = (v2f){sSc * Whh[ri*2+j],  sSc * Whh[rf*2+j]};
    cf.rIFX[l] = (v2f){sSc * Whh[ri*2+jo], sSc * Whh[rf*2+jo]};
    cf.rGOS[l] = (v2f){sTc * Whh[rg*2+j],  sSc * Whh[ro*2+j]};
    cf.rGOX[l] = (v2f){sTc * Whh[rg*2+jo], sSc * Whh[ro*2+jo]};
    cf.bIF[l]  = (v2f){sSc * (bih[ri] + bhh[ri]), sSc * (bih[rf] + bhh[rf])};
    cf.bGO[l]  = (v2f){sTc * (bih[rg] + bhh[rg]), sSc * (bih[ro] + bhh[ro])};
  }

  const int a = k * CHUNK;
  const float* inb  = x      + (size_t)b * (T_LEN * 2);
  float*       outb = out    + (size_t)b * (T_LEN * 2);
  const float* lab  = labels + (size_t)b * (T_LEN * 2);

  // x prefetch ring (8 float2, slot = unroll index => registers)
  float2 pre[8];
#pragma unroll
  for (int u = 0; u < 8; ++u) {
    int tc = a - 45 + u; tc = tc < 0 ? 0 : tc;
    pre[u] = *reinterpret_cast<const float2*>(inb + tc * 2);
  }

  float Cc[4] = {0.f,0.f,0.f,0.f};
  float hS[4] = {0.f,0.f,0.f,0.f};
  float hX[4] = {0.f,0.f,0.f,0.f};
  float lsum  = 0.f;

  // k<2 workers (t_l can be < 0) live in the FIRST BLOCK OF EACH BATCH:
  // blocks 0, 256, 512 (32 workers/block, 256 blocks/batch).
  if ((blockIdx.x & (BLK_PER_BATCH - 1)) == 0)
    scan<true >(cf, j, a, inb, outb, lab, pre, lsum, Cc, hS, hX);
  else
    scan<false>(cf, j, a, inb, outb, lab, pre, lsum, Cc, hS, hX);

  // block = one wave: pure shuffle MSE reduce (deterministic)
  for (int off = 32; off > 0; off >>= 1) lsum += __shfl_down(lsum, off, 64);

  // publish partial; LAST block (done-counter, R3-proven pattern) reduces all
  // 768 partials in fixed order -> deterministic loss, no extra dispatch.
  __shared__ int s_last;
  if (threadIdx.x == 0) {
    part[blockIdx.x] = lsum;
    __threadfence();                                  // release partial (agent)
    const int old = __hip_atomic_fetch_add(done, 1, __ATOMIC_ACQ_REL,
                                           __HIP_MEMORY_SCOPE_AGENT);
    s_last = (old == NBLOCKS - 1) ? 1 : 0;
    if (s_last) __threadfence();                      // acquire all partials
  }
  __syncthreads();
  if (s_last) {
    float v = 0.f;
    for (int i = threadIdx.x; i < NBLOCKS; i += NTHREADS)   // fixed order
      v += __hip_atomic_load(&part[i], __ATOMIC_RELAXED,
                             __HIP_MEMORY_SCOPE_AGENT);
    for (int off = 32; off > 0; off >>= 1) v += __shfl_down(v, off, 64);
    if (threadIdx.x == 0) loss[0] = v * (1.0f / (float)NELEM);
  }
}

extern "C" void kernel_launch(void* const* d_in, const int* in_sizes, int n_in,
                              void* d_out, int out_size, void* d_ws, size_t ws_size,
                              hipStream_t stream) {
  const float* x      = (const float*)d_in[0];
  const float* labels = (const float*)d_in[1];
  const float* Wih    = (const float*)d_in[2];   // [4,8,2]
  const float* Whh    = (const float*)d_in[3];   // [4,8,2]
  const float* bih    = (const float*)d_in[4];   // [4,8]
  const float* bhh    = (const float*)d_in[5];   // [4,8]

  float* out  = (float*)d_out;
  float* loss = out + NELEM;
  float* part = (float*)d_ws;                    // [NBLOCKS]
  int*   done = (int*)(part + NBLOCKS);          // [1]

  hipMemsetAsync(done, 0, sizeof(int), stream);  // in-stream, graph-capturable
  lstm_fused<<<NBLOCKS, NTHREADS, 0, stream>>>(x, out, Wih, Whh, bih, bhh,
                                               labels, part, done, loss);
}

// Round 13
// 29.331 us; speedup vs baseline: 2.1459x; 2.1459x over previous
//
#include <hip/hip_runtime.h>

// LSTMStacked: B=3, T=262144, H=2, L=4.  (R13 = revert to validated R11.)
// Telescoped-warmup fusion, rolled staircase + packed-FMA gates, CHUNK=32,
// 1 wave/SIMD. R12 lesson (confirmed R4): grid-scale agent-scope atomics/
// fences cost tens of us on non-coherent XCD L2s; a dependent 1-block
// dispatch (~4us) is always cheaper -> separate loss_final kernel.
// Cost model (calibrated R5/R10/R11): per-cell wave cost ~190cy (7 trans
// x ~16cy + ~56cy VALU, non-overlapping at 1 wave/SIMD); 272 cells/worker
// -> kernel floor ~21.5us; + loss_final + dispatch ~26-27us structural.
// Schedule (validated R7/R10/R11): t0base=a-45; L1/L2/L3 join at iters
// 8/16/24 (L3 warms 24; absmax floor 4.9e-4 = fp32 rounding for all W>=24);
// store iters 48..79. Layers skewed 1 step => 4 independent cells/iter.
// Masked workers (t_l<0) = k<2 = first block of each batch (0/256/512).

#define T_LEN   262144
#define TMAX    (T_LEN - 1)
#define BATCH   3
#define NCHUNK  8192
#define CHUNK   32
#define NELEM   (BATCH * T_LEN * 2)             // 1572864
#define NTHREADS 64
#define NBLOCKS (BATCH * NCHUNK * 2 / NTHREADS) // 768
#define BLK_PER_BATCH (NBLOCKS / BATCH)         // 256

typedef float v2f __attribute__((ext_vector_type(2)));

static constexpr float L2E = 1.4426950408889634f;
static constexpr float sSc = -L2E;        // sigmoid rows: sig = rcp(1+exp2(-L2E*x))
static constexpr float sTc = 2.0f * L2E;  // tanh rows / scaled-c domain

__device__ __forceinline__ float fexp2(float x) { return __builtin_amdgcn_exp2f(x); }
__device__ __forceinline__ float frcp (float x) { return __builtin_amdgcn_rcpf(x); }

// lane 2i <-> 2i+1 exchange, pure VALU (DPP quad_perm [1,0,3,2]).
__device__ __forceinline__ float pair_swap(float x) {
  return __int_as_float(__builtin_amdgcn_mov_dpp(__float_as_int(x), 0xB1, 0xF, 0xF, true));
}
__device__ __forceinline__ v2f pkfma(v2f a, v2f b, v2f c) {
  return __builtin_elementwise_fma(a, b, c);     // -> v_pk_fma_f32
}
__device__ __forceinline__ v2f splat(float s) { return (v2f){s, s}; }

struct Coef {  // packed pairs: IF = (gate_i, gate_f), GO = (gate_g, gate_o)
  v2f aIFS[4], aIFX[4], rIFS[4], rIFX[4], bIF[4];
  v2f aGOS[4], aGOX[4], rGOS[4], rGOX[4], bGO[4];
};

// One time step over the NL active layers. All cells read PRE-iteration
// state (cn/hn staged, write-back after) => skew semantics, independent cells.
template<int NL, bool MASK, bool STORE>
__device__ __forceinline__ void step(const Coef& cf, int j, int t0v,
    float2& preu, const float* __restrict__ inb, float* __restrict__ outb,
    float lvu, float& lsum,
    float (&Cc)[4], float (&hS)[4], float (&hX)[4])
{
  const float2 xv = preu;
  int tn = t0v + 8;
  if (MASK)  tn = tn < 0 ? 0 : tn;        // only first-block-of-batch path
  if (STORE) tn = tn > TMAX ? TMAX : tn;  // only last-chunk guard
  preu = *reinterpret_cast<const float2*>(inb + tn * 2);

  float cn[4], hn[4];
#pragma unroll
  for (int l = 0; l < NL; ++l) {
    const float iS = (l == 0) ? xv.x : hS[l-1];
    const float iX = (l == 0) ? xv.y : hX[l-1];
    v2f sIF = pkfma(cf.rIFX[l], splat(hX[l]), pkfma(cf.rIFS[l], splat(hS[l]),
              pkfma(cf.aIFX[l], splat(iX), pkfma(cf.aIFS[l], splat(iS), cf.bIF[l]))));
    v2f sGO = pkfma(cf.rGOX[l], splat(hX[l]), pkfma(cf.rGOS[l], splat(hS[l]),
              pkfma(cf.aGOX[l], splat(iX), pkfma(cf.aGOS[l], splat(iS), cf.bGO[l]))));
    const float Ei = fexp2(sIF.x), Ef = fexp2(sIF.y);
    const float Eg = fexp2(sGO.x), Eo = fexp2(sGO.y);
    // Merged cell (validated R7): cn = [Cc*P + sT*(Eg-1)*F1] / (P*F1),
    // P=(1+Ei)(1+Eg), F1=1+Ef;  hn = (Ec-1)/((1+Eo)(1+Ec)), Ec=exp2(cn).
    const float F1 = 1.f + Ef;
    const float P  = (1.f + Ei) * (1.f + Eg);
    const float Nn = fmaf(Cc[l], P, sTc * (Eg - 1.f) * F1);
    cn[l] = Nn * frcp(P * F1);
    const float Ec = fexp2(cn[l]);
    const float Q  = frcp((1.f + Eo) * (1.f + Ec));
    hn[l] = (Ec - 1.f) * Q;
  }
#pragma unroll
  for (int l = 0; l < NL; ++l) {
    if (MASK) {
      const bool act = t0v >= l;          // t_l = t0v - l >= 0
      Cc[l] = act ? cn[l] : 0.f;
      const float hm = act ? hn[l] : 0.f;
      hS[l] = hm; hX[l] = pair_swap(hm);
    } else {
      Cc[l] = cn[l]; hS[l] = hn[l]; hX[l] = pair_swap(hn[l]);
    }
  }
  if (STORE) {
    const float d = hS[3] - lvu;
    lsum = fmaf(d, d, lsum);
    if (j == 0) *reinterpret_cast<float2*>(outb + (t0v - 3) * 2)
                  = make_float2(hS[3], hX[3]);
  }
}

template<bool MASK>
__device__ __forceinline__ void scan(const Coef& cf, int j, int a,
    const float* __restrict__ inb, float* __restrict__ outb,
    const float* __restrict__ lab, float2 (&pre)[8], float& lsum,
    float (&Cc)[4], float (&hS)[4], float (&hX)[4])
{
  const int t0base = a - 45;
  // staircase warm: 8 iters L0; 8 iters L0-1; 8 iters L0-2; 24 iters all-4
#pragma unroll
  for (int u = 0; u < 8; ++u)
    step<1, MASK, false>(cf, j, t0base + u, pre[u], inb, outb, 0.f, lsum, Cc, hS, hX);
#pragma unroll
  for (int u = 0; u < 8; ++u)
    step<2, MASK, false>(cf, j, t0base + 8 + u, pre[u], inb, outb, 0.f, lsum, Cc, hS, hX);
#pragma unroll
  for (int u = 0; u < 8; ++u)
    step<3, MASK, false>(cf, j, t0base + 16 + u, pre[u], inb, outb, 0.f, lsum, Cc, hS, hX);
#pragma clang loop unroll(disable)
  for (int i = 24; i < 48; i += 8) {
#pragma unroll
    for (int u = 0; u < 8; ++u)
      step<4, MASK, false>(cf, j, t0base + i + u, pre[u], inb, outb, 0.f, lsum, Cc, hS, hX);
  }
  // store: 4 rolled passes of 8; labels double-buffered ONE PASS AHEAD so the
  // L2 label-load latency (~200-900 cy) never lands on the recurrence chain.
  float lvu[8];
#pragma unroll
  for (int u = 0; u < 8; ++u) lvu[u] = lab[(a + u) * 2 + j];
#pragma clang loop unroll(disable)
  for (int ip = 0; ip < 4; ++ip) {
    const int ipn = ip < 3 ? ip + 1 : 3;     // last pass re-reads its own (dead)
    float lvn[8];
#pragma unroll
    for (int u = 0; u < 8; ++u) lvn[u] = lab[(a + ipn * 8 + u) * 2 + j];
#pragma unroll
    for (int u = 0; u < 8; ++u)
      step<4, false, true>(cf, j, t0base + 48 + ip * 8 + u, pre[u], inb, outb,
                           lvu[u], lsum, Cc, hS, hX);
#pragma unroll
    for (int u = 0; u < 8; ++u) lvu[u] = lvn[u];
  }
}

__global__ __launch_bounds__(NTHREADS) void lstm_fused(
    const float* __restrict__ x,      // [B,T,2]
    float*       __restrict__ out,    // [B,T,2]
    const float* __restrict__ WihA,   // [4,8,2]
    const float* __restrict__ WhhA,   // [4,8,2]
    const float* __restrict__ bihA,   // [4,8]
    const float* __restrict__ bhhA,   // [4,8]
    const float* __restrict__ labels, // [B,T,2]
    float*       __restrict__ part)   // [NBLOCKS]
{
  const int gt = blockIdx.x * NTHREADS + threadIdx.x;
  const int w  = gt >> 1;            // worker = (batch, chunk)
  const int j  = gt & 1;             // hidden unit owned by this lane
  const int b  = w >> 13;            // w / NCHUNK (8192 workers per batch)
  const int k  = w & (NCHUNK - 1);
  const int jo = j ^ 1;

  Coef cf;
#pragma unroll
  for (int l = 0; l < 4; ++l) {
    const float* Wih = WihA + l * 16;
    const float* Whh = WhhA + l * 16;
    const float* bih = bihA + l * 8;
    const float* bhh = bhhA + l * 8;
    const int ri = j, rf = 2 + j, rg = 4 + j, ro = 6 + j;
    if (l == 0) {    // absolute x columns (iS = x.x, iX = x.y)
      cf.aIFS[0] = (v2f){sSc * Wih[ri*2+0], sSc * Wih[rf*2+0]};
      cf.aIFX[0] = (v2f){sSc * Wih[ri*2+1], sSc * Wih[rf*2+1]};
      cf.aGOS[0] = (v2f){sTc * Wih[rg*2+0], sSc * Wih[ro*2+0]};
      cf.aGOX[0] = (v2f){sTc * Wih[rg*2+1], sSc * Wih[ro*2+1]};
    } else {         // own/cross form (input = lower layer's hS/hX)
      cf.aIFS[l] = (v2f){sSc * Wih[ri*2+j],  sSc * Wih[rf*2+j]};
      cf.aIFX[l] = (v2f){sSc * Wih[ri*2+jo], sSc * Wih[rf*2+jo]};
      cf.aGOS[l] = (v2f){sTc * Wih[rg*2+j],  sSc * Wih[ro*2+j]};
      cf.aGOX[l] = (v2f){sTc * Wih[rg*2+jo], sSc * Wih[ro*2+jo]};
    }
    cf.rIFS[l] = (v2f){sSc * Whh[ri*2+j],  sSc * Whh[rf*2+j]};
    cf.rIFX[l] = (v2f){sSc * Whh[ri*2+jo], sSc * Whh[rf*2+jo]};
    cf.rGOS[l] = (v2f){sTc * Whh[rg*2+j],  sSc * Whh[ro*2+j]};
    cf.rGOX[l] = (v2f){sTc * Whh[rg*2+jo], sSc * Whh[ro*2+jo]};
    cf.bIF[l]  = (v2f){sSc * (bih[ri] + bhh[ri]), sSc * (bih[rf] + bhh[rf])};
    cf.bGO[l]  = (v2f){sTc * (bih[rg] + bhh[rg]), sSc * (bih[ro] + bhh[ro])};
  }

  const int a = k * CHUNK;
  const float* inb  = x      + (size_t)b * (T_LEN * 2);
  float*       outb = out    + (size_t)b * (T_LEN * 2);
  const float* lab  = labels + (size_t)b * (T_LEN * 2);

  // x prefetch ring (8 float2, slot = unroll index => registers)
  float2 pre[8];
#pragma unroll
  for (int u = 0; u < 8; ++u) {
    int tc = a - 45 + u; tc = tc < 0 ? 0 : tc;
    pre[u] = *reinterpret_cast<const float2*>(inb + tc * 2);
  }

  float Cc[4] = {0.f,0.f,0.f,0.f};
  float hS[4] = {0.f,0.f,0.f,0.f};
  float hX[4] = {0.f,0.f,0.f,0.f};
  float lsum  = 0.f;

  // k<2 workers (t_l can be < 0) live in the FIRST BLOCK OF EACH BATCH:
  // blocks 0, 256, 512 (32 workers/block, 256 blocks/batch).
  if ((blockIdx.x & (BLK_PER_BATCH - 1)) == 0)
    scan<true >(cf, j, a, inb, outb, lab, pre, lsum, Cc, hS, hX);
  else
    scan<false>(cf, j, a, inb, outb, lab, pre, lsum, Cc, hS, hX);

  // block = one wave: pure shuffle MSE reduce (deterministic)
  for (int off = 32; off > 0; off >>= 1) lsum += __shfl_down(lsum, off, 64);
  if (threadIdx.x == 0) part[blockIdx.x] = lsum;
}

__global__ __launch_bounds__(256) void loss_final(
    const float* __restrict__ part, float* __restrict__ loss, int n)
{
  float s = 0.f;
  for (int i = threadIdx.x; i < n; i += 256) s += part[i];
  for (int off = 32; off > 0; off >>= 1) s += __shfl_down(s, off, 64);
  __shared__ float ls[4];
  const int lane = threadIdx.x & 63, wv = threadIdx.x >> 6;
  if (lane == 0) ls[wv] = s;
  __syncthreads();
  if (threadIdx.x == 0) loss[0] = (ls[0] + ls[1] + ls[2] + ls[3]) * (1.0f / (float)NELEM);
}

extern "C" void kernel_launch(void* const* d_in, const int* in_sizes, int n_in,
                              void* d_out, int out_size, void* d_ws, size_t ws_size,
                              hipStream_t stream) {
  const float* x      = (const float*)d_in[0];
  const float* labels = (const float*)d_in[1];
  const float* Wih    = (const float*)d_in[2];   // [4,8,2]
  const float* Whh    = (const float*)d_in[3];   // [4,8,2]
  const float* bih    = (const float*)d_in[4];   // [4,8]
  const float* bhh    = (const float*)d_in[5];   // [4,8]

  float* out  = (float*)d_out;
  float* loss = out + NELEM;
  float* part = (float*)d_ws;                    // [NBLOCKS]

  lstm_fused<<<NBLOCKS, NTHREADS, 0, stream>>>(x, out, Wih, Whh, bih, bhh,
                                               labels, part);
  loss_final<<<1, 256, 0, stream>>>(part, loss, NBLOCKS);
}